// Round 8
// baseline (200.746 us; speedup 1.0000x reference)
//
#include <hip/hip_runtime.h>
#include <cstdint>
#include <cstddef>

// ---------------------------------------------------------------------------
// x = mean_i( softmax(q_i K^T / 16) ) @ h   with q = h@Wq, k = h@Wk
//   = sum_j c_j h_j,  c_j = (1/N) sum_i exp(e_ij)/l_i,  l_i = sum_j exp(e_ij)
//
// Round 8: qk_pass byte-identical to R7 (control). Residual attack:
//  - proj fat: grid 128 x 64 rows; h staged once (LDS bf16, pad 264);
//    W B-frags read DIRECT from global fp32 (L2-hot 256 KB, ~2 lines/instr)
//    with on-the-fly RTN bf16 convert -> no W staging at all; 4 phases
//    (which x col-half); proven wave-private LDS repack -> dwordx4 stores.
//    W traffic 131 MB -> 32 MB; kills the scalar-LDS-read inner loop.
//  - finish: 256 blocks x 32 rows, fully unrolled (32 loads in flight).
//
// ws: R5/R7 layout (proven 8,454,144 B high-water):
//   [0,4MB) q bf16 frag-major | [4MB,8MB) k frag-major | l fp32[8192] | c fp32[8192]
// Frag-major (32x32 MFMA A/B layout) per 32-row tile = 16 KB:
//   elem (i,d): tile i>>5, slot (d>>4)*64 + (i&31) + 32*((d>>3)&1), byte d&7;
//   dword index within tile = a0*64 + lane (lane-linear 16B).
// ---------------------------------------------------------------------------

#define N_ROWS 8192
#define DIM    256

typedef __bf16 bf16x8 __attribute__((ext_vector_type(8)));
typedef unsigned short u16x8 __attribute__((ext_vector_type(8)));
typedef float f32x16 __attribute__((ext_vector_type(16)));

__device__ __forceinline__ uint16_t f2bf(float f) {
    uint32_t u = __float_as_uint(f);
    uint32_t r = (u + 0x7fffu + ((u >> 16) & 1u)) >> 16;   // RTN-even
    return (uint16_t)r;
}

__device__ __forceinline__ float fexp2(float x) {
#if __has_builtin(__builtin_amdgcn_exp2f)
    return __builtin_amdgcn_exp2f(x);                      // v_exp_f32 = 2^x
#else
    return __expf(x * 0.69314718056f);
#endif
}

// async global->LDS, 16B/lane; lds dst is wave-uniform base + lane*16
__device__ __forceinline__ void gld16(const void* gsrc, void* ldst) {
    __builtin_amdgcn_global_load_lds(
        (const __attribute__((address_space(1))) unsigned int*)gsrc,
        (__attribute__((address_space(3))) unsigned int*)ldst, 16, 0, 0);
}

// ---------------------------------------------------------------------------
// Kernel 1: q = (h @ Wq)*(log2e/16), k = h @ Wk, bf16 frag-major.
// Grid 128 x 64 rows. h staged once to LDS (bf16, pad 264); per-wave A-frags
// resident (wave>>1 picks rowtile); W read direct from global per B-chunk
// (8 dwords, 2 cache lines per wave-instr, L2-hot); wave&1 picks coltile
// pair. Phases: (Wq,half0),(Wq,half1),(Wk,half0),(Wk,half1).
// Zero-inits l_arr / c_arr / out.
// ---------------------------------------------------------------------------
__global__ __launch_bounds__(256) void proj_kernel(
        const float* __restrict__ h, const float* __restrict__ Wq,
        const float* __restrict__ Wk, uint16_t* __restrict__ qf,
        uint16_t* __restrict__ kf, float* __restrict__ l_arr,
        float* __restrict__ c_arr, float* __restrict__ out) {
    __shared__ alignas(16) uint16_t hb16[64 * 264];   // 33,792 B
    __shared__ alignas(16) uint16_t rep[4][1024];     // 8 KB wave-private repack
    const int tid = threadIdx.x, lane = tid & 63, wave = tid >> 6;
    const int bid = blockIdx.x;

    if (bid < 32)       l_arr[bid * 256 + tid] = 0.0f;
    else if (bid < 64)  c_arr[(bid - 32) * 256 + tid] = 0.0f;
    else if (bid == 64) out[tid] = 0.0f;

    // stage h rows [bid*64, +64) as bf16, coalesced; row stride 264 u16
    for (int i = tid; i < 4096; i += 256) {
        int r = i >> 6, c4 = (i & 63) * 4;
        float4 v = *(const float4*)&h[(size_t)(bid * 64 + r) * DIM + c4];
        ushort4 b;
        b.x = f2bf(v.x); b.y = f2bf(v.y); b.z = f2bf(v.z); b.w = f2bf(v.w);
        *(ushort4*)&hb16[r * 264 + c4] = b;
    }
    __syncthreads();

    // A-fragments: this wave's rowtile (32 rows x K=256), from LDS
    bf16x8 afrag[16];
    const int lr = (wave >> 1) * 32 + (lane & 31);
#pragma unroll
    for (int a0 = 0; a0 < 16; a0++) {
        int c0 = a0 * 16 + (lane >> 5) * 8;
        afrag[a0] = __builtin_bit_cast(bf16x8, *(const u16x8*)&hb16[lr * 264 + c0]);
    }
    const int rtg = bid * 2 + (wave >> 1);            // global rowtile

#pragma unroll 1
    for (int ph = 0; ph < 4; ph++) {
        const int which = ph >> 1, p = ph & 1;
        const float* __restrict__ W = which ? Wk : Wq;
        uint16_t* __restrict__ dst = which ? kf : qf;
        const float scale = which ? 1.0f : (0.0625f * 1.44269504089f);
#pragma unroll
        for (int cti = 0; cti < 2; cti++) {
            const int ctl = (wave & 1) * 2 + cti;     // coltile in half, 0..3
            const int cl = ctl * 32 + (lane & 31);    // col in half, 0..127
            f32x16 acc;
#pragma unroll
            for (int i = 0; i < 16; i++) acc[i] = 0.0f;
#pragma unroll
            for (int a0 = 0; a0 < 16; a0++) {
                const int kb = a0 * 16 + (lane >> 5) * 8;
                u16x8 f;
#pragma unroll
                for (int j = 0; j < 8; j++)
                    f[j] = f2bf(W[(size_t)(kb + j) * DIM + p * 128 + cl]);
                acc = __builtin_amdgcn_mfma_f32_32x32x16_bf16(
                    afrag[a0], __builtin_bit_cast(bf16x8, f), acc, 0, 0, 0);
            }
            // repack C-tile (32 rows x 32 cols) via wave-private LDS
            const int dcl = lane & 31;
            const int a0o = dcl >> 4, hi = (dcl >> 3) & 1, jj = dcl & 7;
            const int ilb = 4 * (lane >> 5);
#pragma unroll
            for (int reg = 0; reg < 16; reg++) {
                int il = ilb + (reg & 3) + 8 * (reg >> 2);
                rep[wave][(size_t)((a0o * 64) + il + 32 * hi) * 8 + jj] =
                    f2bf(acc[reg] * scale);
            }
            const uint4* rv = (const uint4*)&rep[wave][0];  // wave-local RAW
            uint4* gp = (uint4*)(dst + (size_t)rtg * 8192 +
                                 (size_t)(p * 8 + ctl * 2) * 512);
            gp[lane * 2]     = rv[lane * 2];
            gp[lane * 2 + 1] = rv[lane * 2 + 1];
        }
    }
}

// ---------------------------------------------------------------------------
// Kernels 2/3 (R7 verbatim): two QK^T passes. Grid 512 = 32 rowblocks(256
// rows) x 16 colchunks(512 cols). k tile (32 cols, 16KB) staged to LDS once
// per block (double-buffered async global_load_lds, 1 barrier/tile),
// consumed by 4 waves x 2 rowtiles = 128 MFMAs/tile. q: 2 rowtiles/wave
// resident. MODE 0: l_i row sums. MODE 1: c_j weighted col sums.
// ---------------------------------------------------------------------------
template <int MODE>
__global__ __launch_bounds__(256, 2) void qk_pass(
        const uint16_t* __restrict__ qf, const uint16_t* __restrict__ kf,
        float* __restrict__ l_arr, float* __restrict__ c_arr) {
    __shared__ alignas(16) uint16_t ktile[2][8192];   // 2 x 16 KB
    __shared__ float c_lds[512];
    const int tid = threadIdx.x, lane = tid & 63, wave = tid >> 6;
    const int bid = blockIdx.x;
    const int cc = bid & 15, rb = bid >> 4;
    const int t0 = rb * 8 + wave * 2;                 // wave's rowtiles t0, t0+1
    const int row0 = t0 * 32;

    // resident q: 2 rowtiles x 16 K-chunks = 128 regs
    const uint4* qp = (const uint4*)qf;
    bf16x8 q0[16], q1[16];
#pragma unroll
    for (int a0 = 0; a0 < 16; a0++) {
        q0[a0] = __builtin_bit_cast(bf16x8, qp[(size_t)t0 * 1024 + a0 * 64 + lane]);
        q1[a0] = __builtin_bit_cast(bf16x8, qp[(size_t)(t0 + 1) * 1024 + a0 * 64 + lane]);
    }

    float rs0[16], rs1[16];   // MODE 0 partials
    float rr0[16], rr1[16];   // MODE 1: 1/(N*l_i)
    if (MODE == 0) {
#pragma unroll
        for (int r = 0; r < 16; r++) { rs0[r] = 0.0f; rs1[r] = 0.0f; }
    } else {
#pragma unroll
        for (int r = 0; r < 16; r++) {
            int ro = (r & 3) + 8 * (r >> 2) + 4 * (lane >> 5);
            rr0[r] = 1.0f / (8192.0f * l_arr[row0 + ro]);
            rr1[r] = 1.0f / (8192.0f * l_arr[row0 + 32 + ro]);
        }
        for (int i = tid; i < 512; i += 256) c_lds[i] = 0.0f;
    }

    const char* ksrc = (const char*)kf + (size_t)cc * 16 * 16384;  // 16 tiles

    {   // prologue: stage tile 0 -> buffer 0
        const char* s0 = ksrc + wave * 4096 + lane * 16;
        char* d0 = (char*)&ktile[0][0] + wave * 4096;
#pragma unroll
        for (int it = 0; it < 4; it++) gld16(s0 + it * 1024, d0 + it * 1024);
    }

    for (int t = 0; t < 16; t++) {
        __syncthreads();          // vmcnt drained: tile t staged, and all
                                  // waves done reading the other buffer
        if (t < 15) {             // prefetch t+1; lands during this compute
            const char* sn = ksrc + (t + 1) * 16384 + wave * 4096 + lane * 16;
            char* dn = (char*)&ktile[(t + 1) & 1][0] + wave * 4096;
#pragma unroll
            for (int it = 0; it < 4; it++) gld16(sn + it * 1024, dn + it * 1024);
        }

        const uint16_t* kt = &ktile[t & 1][0];
        f32x16 acc0, acc1;        // 2 independent chains (one per rowtile)
#pragma unroll
        for (int i = 0; i < 16; i++) { acc0[i] = 0.0f; acc1[i] = 0.0f; }
#pragma unroll
        for (int a0 = 0; a0 < 16; a0++) {
            bf16x8 b = __builtin_bit_cast(bf16x8,
                *(const u16x8*)&kt[(size_t)(a0 * 64 + lane) * 8]);
            acc0 = __builtin_amdgcn_mfma_f32_32x32x16_bf16(q0[a0], b, acc0, 0, 0, 0);
            acc1 = __builtin_amdgcn_mfma_f32_32x32x16_bf16(q1[a0], b, acc1, 0, 0, 0);
        }

        if (MODE == 0) {
#pragma unroll
            for (int r = 0; r < 16; r++) {
                rs0[r] += fexp2(acc0[r]);
                rs1[r] += fexp2(acc1[r]);
            }
        } else {
            float sv = 0.0f;
#pragma unroll
            for (int r = 0; r < 16; r++) {
                sv += fexp2(acc0[r]) * rr0[r];
                sv += fexp2(acc1[r]) * rr1[r];
            }
            sv += __shfl_xor(sv, 32);                 // fold row halves per col
            if (lane < 32) atomicAdd(&c_lds[t * 32 + lane], sv);
        }
    }

    if (MODE == 0) {
#pragma unroll
        for (int r = 0; r < 16; r++) {
            float v0 = rs0[r], v1 = rs1[r];
            v0 += __shfl_xor(v0, 1);  v0 += __shfl_xor(v0, 2);
            v0 += __shfl_xor(v0, 4);  v0 += __shfl_xor(v0, 8);
            v0 += __shfl_xor(v0, 16);
            v1 += __shfl_xor(v1, 1);  v1 += __shfl_xor(v1, 2);
            v1 += __shfl_xor(v1, 4);  v1 += __shfl_xor(v1, 8);
            v1 += __shfl_xor(v1, 16);
            if ((lane & 31) == 0) {
                int ro = (r & 3) + 8 * (r >> 2) + 4 * (lane >> 5);
                atomicAdd(&l_arr[row0 + ro], v0);
                atomicAdd(&l_arr[row0 + 32 + ro], v1);
            }
        }
    } else {
        __syncthreads();
        for (int i = tid; i < 512; i += 256)
            atomicAdd(&c_arr[cc * 512 + i], c_lds[i]);
    }
}

// ---------------------------------------------------------------------------
// Kernel 4: x = c @ h. 256 blocks x 32 rows, fully unrolled -> 32 independent
// loads in flight per thread (hides HBM/L2 latency); coalesced h reads.
// ---------------------------------------------------------------------------
__global__ __launch_bounds__(256) void finish_kernel(
        const float* __restrict__ h, const float* __restrict__ c_arr,
        float* __restrict__ out) {
    const int d = threadIdx.x;
    const int j0 = blockIdx.x * 32;
    float acc = 0.0f;
#pragma unroll
    for (int jj = 0; jj < 32; jj++)
        acc += c_arr[j0 + jj] * h[(size_t)(j0 + jj) * DIM + d];
    atomicAdd(&out[d], acc);
}

// ---------------------------------------------------------------------------
extern "C" void kernel_launch(void* const* d_in, const int* in_sizes, int n_in,
                              void* d_out, int out_size, void* d_ws, size_t ws_size,
                              hipStream_t stream) {
    const float* h  = (const float*)d_in[0];
    const float* Wq = (const float*)d_in[1];
    const float* Wk = (const float*)d_in[2];

    // ws layout identical to R5/R7 (proven high-water 8,454,144 B)
    uint16_t* qf = (uint16_t*)d_ws;
    uint16_t* kf = qf + (size_t)N_ROWS * DIM;                  // +4 MB
    float* l_arr = (float*)((char*)d_ws + (size_t)8 * 1024 * 1024);
    float* c_arr = l_arr + N_ROWS;
    float* out = (float*)d_out;

    proj_kernel<<<128, 256, 0, stream>>>(h, Wq, Wk, qf, kf, l_arr, c_arr, out);
    qk_pass<0><<<512, 256, 0, stream>>>(qf, kf, l_arr, c_arr);
    qk_pass<1><<<512, 256, 0, stream>>>(qf, kf, l_arr, c_arr);
    finish_kernel<<<256, 256, 0, stream>>>(h, c_arr, out);
}

// Round 10
// 159.199 us; speedup vs baseline: 1.2610x; 1.2610x over previous
//
#include <hip/hip_runtime.h>
#include <cstdint>
#include <cstddef>

// ---------------------------------------------------------------------------
// x = mean_i( softmax(q_i K^T / 16) ) @ h   with q = h@Wq, k = h@Wk
//   = sum_j c_j h_j,  c_j = (1/N) sum_i exp(e_ij)/l_i,  l_i = sum_j exp(e_ij)
//
// Round 10: bisection round. R6/R9 (frag-layout W staging) both NaN'd; the
// index algebra audits clean, so instead of betting on it again, proj reverts
// to R8's PASSING per-lane data path verbatim and changes ONLY distribution:
//   grid 1024 = 256 rowtiles x 4 phases (which x half); block = 1 rowtile,
//   4 waves = 4 coltiles. Per-wave chain: 128 independent scalar W loads
//   (vs R8's 1024) + 16 MFMA. All 256 CUs busy (vs 128).
// qk_pass + finish byte-identical to R7/R8 (controls).
//
// ws: R5/R7/R8 layout (proven 8,454,144 B high-water):
//   [0,4MB) q bf16 frag-major | [4MB,8MB) k frag-major | l fp32[8192] | c fp32[8192]
// Frag-major (32x32 MFMA A/B layout) per 32-row tile = 16 KB:
//   elem (i,d): tile i>>5, slot (d>>4)*64 + (i&31) + 32*((d>>3)&1), byte d&7;
//   dword index within tile = a0*64 + lane (lane-linear 16B).
// ---------------------------------------------------------------------------

#define N_ROWS 8192
#define DIM    256

typedef __bf16 bf16x8 __attribute__((ext_vector_type(8)));
typedef unsigned short u16x8 __attribute__((ext_vector_type(8)));
typedef float f32x16 __attribute__((ext_vector_type(16)));

__device__ __forceinline__ uint16_t f2bf(float f) {
    uint32_t u = __float_as_uint(f);
    uint32_t r = (u + 0x7fffu + ((u >> 16) & 1u)) >> 16;   // RTN-even
    return (uint16_t)r;
}

__device__ __forceinline__ float fexp2(float x) {
#if __has_builtin(__builtin_amdgcn_exp2f)
    return __builtin_amdgcn_exp2f(x);                      // v_exp_f32 = 2^x
#else
    return __expf(x * 0.69314718056f);
#endif
}

// async global->LDS, 16B/lane; lds dst is wave-uniform base + lane*16
__device__ __forceinline__ void gld16(const void* gsrc, void* ldst) {
    __builtin_amdgcn_global_load_lds(
        (const __attribute__((address_space(1))) unsigned int*)gsrc,
        (__attribute__((address_space(3))) unsigned int*)ldst, 16, 0, 0);
}

// ---------------------------------------------------------------------------
// Kernel 1: proj, R8 data path / R10 distribution. Grid 1024:
// bid = rt*4 + ph, ph = which*2 + p. Block: rowtile rt, one (W, col-half);
// wave = coltile ctl in the half. Per-lane W access, repack, and store are
// R8-verbatim. Zero-inits l_arr / c_arr / out (bid 0..64 guard).
// ---------------------------------------------------------------------------
__global__ __launch_bounds__(256) void proj_kernel(
        const float* __restrict__ h, const float* __restrict__ Wq,
        const float* __restrict__ Wk, uint16_t* __restrict__ qf,
        uint16_t* __restrict__ kf, float* __restrict__ l_arr,
        float* __restrict__ c_arr, float* __restrict__ out) {
    __shared__ alignas(16) uint16_t rep[4][1024];     // 8 KB wave-private repack
    const int tid = threadIdx.x, lane = tid & 63, wave = tid >> 6;
    const int bid = blockIdx.x;
    const int rt = bid >> 2, ph = bid & 3;
    const int which = ph >> 1, p = ph & 1;

    if (bid < 32)       l_arr[bid * 256 + tid] = 0.0f;
    else if (bid < 64)  c_arr[(bid - 32) * 256 + tid] = 0.0f;
    else if (bid == 64) out[tid] = 0.0f;

    const float* __restrict__ W = which ? Wk : Wq;
    uint16_t* __restrict__ dst = which ? kf : qf;
    const float scale = which ? 1.0f : (0.0625f * 1.44269504089f);

    // A-fragments: rowtile rt direct from global h (R8-verbatim indexing)
    bf16x8 afrag[16];
    {
        const float* hp = h + (size_t)(rt * 32 + (lane & 31)) * DIM;
#pragma unroll
        for (int a0 = 0; a0 < 16; a0++) {
            const int c0 = a0 * 16 + (lane >> 5) * 8;
            float4 f0 = *(const float4*)(hp + c0);
            float4 f1 = *(const float4*)(hp + c0 + 4);
            u16x8 f;
            f[0] = f2bf(f0.x); f[1] = f2bf(f0.y); f[2] = f2bf(f0.z); f[3] = f2bf(f0.w);
            f[4] = f2bf(f1.x); f[5] = f2bf(f1.y); f[6] = f2bf(f1.z); f[7] = f2bf(f1.w);
            afrag[a0] = __builtin_bit_cast(bf16x8, f);
        }
    }

    const int ctl = wave;                             // coltile in half, 0..3
    const int cl = ctl * 32 + (lane & 31);            // col in half, 0..127
    f32x16 acc;
#pragma unroll
    for (int i = 0; i < 16; i++) acc[i] = 0.0f;
#pragma unroll
    for (int a0 = 0; a0 < 16; a0++) {
        const int kb = a0 * 16 + (lane >> 5) * 8;
        u16x8 f;
#pragma unroll
        for (int j = 0; j < 8; j++)
            f[j] = f2bf(W[(size_t)(kb + j) * DIM + p * 128 + cl]);
        acc = __builtin_amdgcn_mfma_f32_32x32x16_bf16(
            afrag[a0], __builtin_bit_cast(bf16x8, f), acc, 0, 0, 0);
    }

    // repack C-tile (32 rows x 32 cols) via wave-private LDS (R8-verbatim)
    {
        const int dcl = lane & 31;
        const int a0o = dcl >> 4, hi = (dcl >> 3) & 1, jj = dcl & 7;
        const int ilb = 4 * (lane >> 5);
#pragma unroll
        for (int reg = 0; reg < 16; reg++) {
            int il = ilb + (reg & 3) + 8 * (reg >> 2);
            rep[wave][(size_t)((a0o * 64) + il + 32 * hi) * 8 + jj] =
                f2bf(acc[reg] * scale);
        }
        const uint4* rv = (const uint4*)&rep[wave][0];  // wave-local RAW
        uint4* gp = (uint4*)(dst + (size_t)rt * 8192 +
                             (size_t)(p * 4 + ctl) * 1024);
        gp[lane * 2]     = rv[lane * 2];
        gp[lane * 2 + 1] = rv[lane * 2 + 1];
    }
}

// ---------------------------------------------------------------------------
// Kernels 2/3 (R7/R8 verbatim): two QK^T passes. Grid 512 = 32 rowblocks(256
// rows) x 16 colchunks(512 cols). k tile (32 cols, 16KB) staged to LDS once
// per block (double-buffered async global_load_lds, 1 barrier/tile),
// consumed by 4 waves x 2 rowtiles = 128 MFMAs/tile. q: 2 rowtiles/wave
// resident. MODE 0: l_i row sums. MODE 1: c_j weighted col sums.
// ---------------------------------------------------------------------------
template <int MODE>
__global__ __launch_bounds__(256, 2) void qk_pass(
        const uint16_t* __restrict__ qf, const uint16_t* __restrict__ kf,
        float* __restrict__ l_arr, float* __restrict__ c_arr) {
    __shared__ alignas(16) uint16_t ktile[2][8192];   // 2 x 16 KB
    __shared__ float c_lds[512];
    const int tid = threadIdx.x, lane = tid & 63, wave = tid >> 6;
    const int bid = blockIdx.x;
    const int cc = bid & 15, rb = bid >> 4;
    const int t0 = rb * 8 + wave * 2;                 // wave's rowtiles t0, t0+1
    const int row0 = t0 * 32;

    // resident q: 2 rowtiles x 16 K-chunks = 128 regs
    const uint4* qp = (const uint4*)qf;
    bf16x8 q0[16], q1[16];
#pragma unroll
    for (int a0 = 0; a0 < 16; a0++) {
        q0[a0] = __builtin_bit_cast(bf16x8, qp[(size_t)t0 * 1024 + a0 * 64 + lane]);
        q1[a0] = __builtin_bit_cast(bf16x8, qp[(size_t)(t0 + 1) * 1024 + a0 * 64 + lane]);
    }

    float rs0[16], rs1[16];   // MODE 0 partials
    float rr0[16], rr1[16];   // MODE 1: 1/(N*l_i)
    if (MODE == 0) {
#pragma unroll
        for (int r = 0; r < 16; r++) { rs0[r] = 0.0f; rs1[r] = 0.0f; }
    } else {
#pragma unroll
        for (int r = 0; r < 16; r++) {
            int ro = (r & 3) + 8 * (r >> 2) + 4 * (lane >> 5);
            rr0[r] = 1.0f / (8192.0f * l_arr[row0 + ro]);
            rr1[r] = 1.0f / (8192.0f * l_arr[row0 + 32 + ro]);
        }
        for (int i = tid; i < 512; i += 256) c_lds[i] = 0.0f;
    }

    const char* ksrc = (const char*)kf + (size_t)cc * 16 * 16384;  // 16 tiles

    {   // prologue: stage tile 0 -> buffer 0
        const char* s0 = ksrc + wave * 4096 + lane * 16;
        char* d0 = (char*)&ktile[0][0] + wave * 4096;
#pragma unroll
        for (int it = 0; it < 4; it++) gld16(s0 + it * 1024, d0 + it * 1024);
    }

    for (int t = 0; t < 16; t++) {
        __syncthreads();          // vmcnt drained: tile t staged, and all
                                  // waves done reading the other buffer
        if (t < 15) {             // prefetch t+1; lands during this compute
            const char* sn = ksrc + (t + 1) * 16384 + wave * 4096 + lane * 16;
            char* dn = (char*)&ktile[(t + 1) & 1][0] + wave * 4096;
#pragma unroll
            for (int it = 0; it < 4; it++) gld16(sn + it * 1024, dn + it * 1024);
        }

        const uint16_t* kt = &ktile[t & 1][0];
        f32x16 acc0, acc1;        // 2 independent chains (one per rowtile)
#pragma unroll
        for (int i = 0; i < 16; i++) { acc0[i] = 0.0f; acc1[i] = 0.0f; }
#pragma unroll
        for (int a0 = 0; a0 < 16; a0++) {
            bf16x8 b = __builtin_bit_cast(bf16x8,
                *(const u16x8*)&kt[(size_t)(a0 * 64 + lane) * 8]);
            acc0 = __builtin_amdgcn_mfma_f32_32x32x16_bf16(q0[a0], b, acc0, 0, 0, 0);
            acc1 = __builtin_amdgcn_mfma_f32_32x32x16_bf16(q1[a0], b, acc1, 0, 0, 0);
        }

        if (MODE == 0) {
#pragma unroll
            for (int r = 0; r < 16; r++) {
                rs0[r] += fexp2(acc0[r]);
                rs1[r] += fexp2(acc1[r]);
            }
        } else {
            float sv = 0.0f;
#pragma unroll
            for (int r = 0; r < 16; r++) {
                sv += fexp2(acc0[r]) * rr0[r];
                sv += fexp2(acc1[r]) * rr1[r];
            }
            sv += __shfl_xor(sv, 32);                 // fold row halves per col
            if (lane < 32) atomicAdd(&c_lds[t * 32 + lane], sv);
        }
    }

    if (MODE == 0) {
#pragma unroll
        for (int r = 0; r < 16; r++) {
            float v0 = rs0[r], v1 = rs1[r];
            v0 += __shfl_xor(v0, 1);  v0 += __shfl_xor(v0, 2);
            v0 += __shfl_xor(v0, 4);  v0 += __shfl_xor(v0, 8);
            v0 += __shfl_xor(v0, 16);
            v1 += __shfl_xor(v1, 1);  v1 += __shfl_xor(v1, 2);
            v1 += __shfl_xor(v1, 4);  v1 += __shfl_xor(v1, 8);
            v1 += __shfl_xor(v1, 16);
            if ((lane & 31) == 0) {
                int ro = (r & 3) + 8 * (r >> 2) + 4 * (lane >> 5);
                atomicAdd(&l_arr[row0 + ro], v0);
                atomicAdd(&l_arr[row0 + 32 + ro], v1);
            }
        }
    } else {
        __syncthreads();
        for (int i = tid; i < 512; i += 256)
            atomicAdd(&c_arr[cc * 512 + i], c_lds[i]);
    }
}

// ---------------------------------------------------------------------------
// Kernel 4 (R8 verbatim): x = c @ h. 256 blocks x 32 rows, fully unrolled.
// ---------------------------------------------------------------------------
__global__ __launch_bounds__(256) void finish_kernel(
        const float* __restrict__ h, const float* __restrict__ c_arr,
        float* __restrict__ out) {
    const int d = threadIdx.x;
    const int j0 = blockIdx.x * 32;
    float acc = 0.0f;
#pragma unroll
    for (int jj = 0; jj < 32; jj++)
        acc += c_arr[j0 + jj] * h[(size_t)(j0 + jj) * DIM + d];
    atomicAdd(&out[d], acc);
}

// ---------------------------------------------------------------------------
extern "C" void kernel_launch(void* const* d_in, const int* in_sizes, int n_in,
                              void* d_out, int out_size, void* d_ws, size_t ws_size,
                              hipStream_t stream) {
    const float* h  = (const float*)d_in[0];
    const float* Wq = (const float*)d_in[1];
    const float* Wk = (const float*)d_in[2];

    // ws layout identical to R5/R7/R8 (proven high-water 8,454,144 B)
    uint16_t* qf = (uint16_t*)d_ws;
    uint16_t* kf = qf + (size_t)N_ROWS * DIM;                  // +4 MB
    float* l_arr = (float*)((char*)d_ws + (size_t)8 * 1024 * 1024);
    float* c_arr = l_arr + N_ROWS;
    float* out = (float*)d_out;

    proj_kernel<<<1024, 256, 0, stream>>>(h, Wq, Wk, qf, kf, l_arr, c_arr, out);
    qk_pass<0><<<512, 256, 0, stream>>>(qf, kf, l_arr, c_arr);
    qk_pass<1><<<512, 256, 0, stream>>>(qf, kf, l_arr, c_arr);
    finish_kernel<<<256, 256, 0, stream>>>(h, c_arr, out);
}

// Round 11
// 155.823 us; speedup vs baseline: 1.2883x; 1.0217x over previous
//
#include <hip/hip_runtime.h>
#include <cstdint>
#include <cstddef>

// ---------------------------------------------------------------------------
// x = mean_i( softmax(q_i K^T / 16) ) @ h   with q = h@Wq, k = h@Wk
//   = sum_j c_j h_j,  c_j = (1/N) sum_i exp(e_ij)/l_i,  l_i = sum_j exp(e_ij)
//
// Round 11 (two independent changes, separately instrumented):
//  - proj: R10 verbatim EXCEPT afrag source = R5/R7's proven h-LDS staging
//    (coalesced float4 -> stride-260 LDS -> lane-local reads). Fixes the
//    32-line/instr uncoalesced h reads (1KB lane stride, 4x overfetch).
//  - qk_pass: 2-tile barrier groups. 32 KB staged per barrier (2 k-tiles,
//    2x32KB double buffer), 8 barriers/pass instead of 16; within a group
//    tile-A's exp epilogue overlaps tile-B's ds_reads (no barrier between).
//    All fragment/epilogue/reduction code byte-identical to R7-R10.
//
// ws: R5..R10 layout (proven 8,454,144 B high-water):
//   [0,4MB) q bf16 frag-major | [4MB,8MB) k frag-major | l fp32[8192] | c fp32[8192]
// Frag-major (32x32 MFMA A/B layout) per 32-row tile = 16 KB:
//   elem (i,d): tile i>>5, slot (d>>4)*64 + (i&31) + 32*((d>>3)&1), byte d&7;
//   dword index within tile = a0*64 + lane (lane-linear 16B).
// ---------------------------------------------------------------------------

#define N_ROWS 8192
#define DIM    256

typedef __bf16 bf16x8 __attribute__((ext_vector_type(8)));
typedef unsigned short u16x8 __attribute__((ext_vector_type(8)));
typedef float f32x16 __attribute__((ext_vector_type(16)));

__device__ __forceinline__ uint16_t f2bf(float f) {
    uint32_t u = __float_as_uint(f);
    uint32_t r = (u + 0x7fffu + ((u >> 16) & 1u)) >> 16;   // RTN-even
    return (uint16_t)r;
}

__device__ __forceinline__ float fexp2(float x) {
#if __has_builtin(__builtin_amdgcn_exp2f)
    return __builtin_amdgcn_exp2f(x);                      // v_exp_f32 = 2^x
#else
    return __expf(x * 0.69314718056f);
#endif
}

// async global->LDS, 16B/lane; lds dst is wave-uniform base + lane*16
__device__ __forceinline__ void gld16(const void* gsrc, void* ldst) {
    __builtin_amdgcn_global_load_lds(
        (const __attribute__((address_space(1))) unsigned int*)gsrc,
        (__attribute__((address_space(3))) unsigned int*)ldst, 16, 0, 0);
}

// ---------------------------------------------------------------------------
// Kernel 1: proj. Grid 1024: bid = rt*4 + ph, ph = which*2 + p. Block: one
// rowtile, one (W, col-half); wave = coltile. h staged coalesced to LDS
// (stride-260 fp32, R5/R7-proven), afrags read lane-locally from LDS; W
// per-lane scalar loads (2 full lines/instr, R8/R10-proven); repack + store
// R8/R10-verbatim. Zero-inits l_arr / c_arr / out.
// ---------------------------------------------------------------------------
__global__ __launch_bounds__(256) void proj_kernel(
        const float* __restrict__ h, const float* __restrict__ Wq,
        const float* __restrict__ Wk, uint16_t* __restrict__ qf,
        uint16_t* __restrict__ kf, float* __restrict__ l_arr,
        float* __restrict__ c_arr, float* __restrict__ out) {
    __shared__ alignas(16) float hbf[32 * 260];       // 33.3 KB h stage
    __shared__ alignas(16) uint16_t rep[4][1024];     // 8 KB wave-private repack
    const int tid = threadIdx.x, lane = tid & 63, wave = tid >> 6;
    const int bid = blockIdx.x;
    const int rt = bid >> 2, ph = bid & 3;
    const int which = ph >> 1, p = ph & 1;

    if (bid < 32)       l_arr[bid * 256 + tid] = 0.0f;
    else if (bid < 64)  c_arr[(bid - 32) * 256 + tid] = 0.0f;
    else if (bid == 64) out[tid] = 0.0f;

    const float* __restrict__ W = which ? Wk : Wq;
    uint16_t* __restrict__ dst = which ? kf : qf;
    const float scale = which ? 1.0f : (0.0625f * 1.44269504089f);

    // ---- stage h rows (32 x 256 fp32) into LDS, coalesced; stride 260 ----
    for (int i = tid; i < 2048; i += 256) {
        int r = i >> 6, c = (i & 63) * 4;
        *(float4*)&hbf[r * 260 + c] = *(const float4*)&h[(size_t)(rt * 32 + r) * DIM + c];
    }
    __syncthreads();

    // A-fragments from LDS (R5/R7-proven indexing)
    bf16x8 afrag[16];
    {
        const int r = lane & 31;
#pragma unroll
        for (int a0 = 0; a0 < 16; a0++) {
            const int c0 = a0 * 16 + (lane >> 5) * 8;
            float4 f0 = *(const float4*)&hbf[r * 260 + c0];
            float4 f1 = *(const float4*)&hbf[r * 260 + c0 + 4];
            u16x8 f;
            f[0] = f2bf(f0.x); f[1] = f2bf(f0.y); f[2] = f2bf(f0.z); f[3] = f2bf(f0.w);
            f[4] = f2bf(f1.x); f[5] = f2bf(f1.y); f[6] = f2bf(f1.z); f[7] = f2bf(f1.w);
            afrag[a0] = __builtin_bit_cast(bf16x8, f);
        }
    }

    const int ctl = wave;                             // coltile in half, 0..3
    const int cl = ctl * 32 + (lane & 31);            // col in half, 0..127
    f32x16 acc;
#pragma unroll
    for (int i = 0; i < 16; i++) acc[i] = 0.0f;
#pragma unroll
    for (int a0 = 0; a0 < 16; a0++) {
        const int kb = a0 * 16 + (lane >> 5) * 8;
        u16x8 f;
#pragma unroll
        for (int j = 0; j < 8; j++)
            f[j] = f2bf(W[(size_t)(kb + j) * DIM + p * 128 + cl]);
        acc = __builtin_amdgcn_mfma_f32_32x32x16_bf16(
            afrag[a0], __builtin_bit_cast(bf16x8, f), acc, 0, 0, 0);
    }

    // repack C-tile (32 rows x 32 cols) via wave-private LDS (R8/R10-verbatim)
    {
        const int dcl = lane & 31;
        const int a0o = dcl >> 4, hi = (dcl >> 3) & 1, jj = dcl & 7;
        const int ilb = 4 * (lane >> 5);
#pragma unroll
        for (int reg = 0; reg < 16; reg++) {
            int il = ilb + (reg & 3) + 8 * (reg >> 2);
            rep[wave][(size_t)((a0o * 64) + il + 32 * hi) * 8 + jj] =
                f2bf(acc[reg] * scale);
        }
        const uint4* rv = (const uint4*)&rep[wave][0];  // wave-local RAW
        uint4* gp = (uint4*)(dst + (size_t)rt * 8192 +
                             (size_t)(p * 4 + ctl) * 1024);
        gp[lane * 2]     = rv[lane * 2];
        gp[lane * 2 + 1] = rv[lane * 2 + 1];
    }
}

// ---------------------------------------------------------------------------
// Kernels 2/3: two QK^T passes, 2-tile barrier groups. Grid 512 = 32
// rowblocks(256 rows) x 16 colchunks(512 cols). Per barrier: 32 KB (2 k-tiles)
// staged via async global_load_lds into 2x32KB double buffer; 8 barriers/pass.
// Within a group tile-A epilogue overlaps tile-B ds_reads (no barrier).
// q: 2 rowtiles/wave resident. MODE 0: l_i row sums. MODE 1: c_j col sums.
// ---------------------------------------------------------------------------
template <int MODE>
__global__ __launch_bounds__(256, 2) void qk_pass(
        const uint16_t* __restrict__ qf, const uint16_t* __restrict__ kf,
        float* __restrict__ l_arr, float* __restrict__ c_arr) {
    __shared__ alignas(16) uint16_t ktile[2][16384];  // 2 x 32 KB (2 tiles each)
    __shared__ float c_lds[512];
    const int tid = threadIdx.x, lane = tid & 63, wave = tid >> 6;
    const int bid = blockIdx.x;
    const int cc = bid & 15, rb = bid >> 4;
    const int t0 = rb * 8 + wave * 2;                 // wave's rowtiles t0, t0+1
    const int row0 = t0 * 32;

    // resident q: 2 rowtiles x 16 K-chunks = 128 regs
    const uint4* qp = (const uint4*)qf;
    bf16x8 q0[16], q1[16];
#pragma unroll
    for (int a0 = 0; a0 < 16; a0++) {
        q0[a0] = __builtin_bit_cast(bf16x8, qp[(size_t)t0 * 1024 + a0 * 64 + lane]);
        q1[a0] = __builtin_bit_cast(bf16x8, qp[(size_t)(t0 + 1) * 1024 + a0 * 64 + lane]);
    }

    float rs0[16], rs1[16];   // MODE 0 partials
    float rr0[16], rr1[16];   // MODE 1: 1/(N*l_i)
    if (MODE == 0) {
#pragma unroll
        for (int r = 0; r < 16; r++) { rs0[r] = 0.0f; rs1[r] = 0.0f; }
    } else {
#pragma unroll
        for (int r = 0; r < 16; r++) {
            int ro = (r & 3) + 8 * (r >> 2) + 4 * (lane >> 5);
            rr0[r] = 1.0f / (8192.0f * l_arr[row0 + ro]);
            rr1[r] = 1.0f / (8192.0f * l_arr[row0 + 32 + ro]);
        }
        for (int i = tid; i < 512; i += 256) c_lds[i] = 0.0f;
    }

    const char* ksrc = (const char*)kf + (size_t)cc * 16 * 16384;  // 16 tiles

    {   // prologue: stage tiles 0,1 -> buffer 0 (8 async 1KB wave-copies)
        const char* s0 = ksrc + wave * 4096 + lane * 16;
        char* d0 = (char*)&ktile[0][0] + wave * 4096;
#pragma unroll
        for (int sub = 0; sub < 2; sub++)
#pragma unroll
            for (int it = 0; it < 4; it++)
                gld16(s0 + sub * 16384 + it * 1024, d0 + sub * 16384 + it * 1024);
    }

    for (int g = 0; g < 8; g++) {
        __syncthreads();          // vmcnt drained: group g staged; other
                                  // buffer's readers all done
        if (g < 7) {              // prefetch group g+1 (tiles 2g+2, 2g+3)
            const char* sn = ksrc + (size_t)(2 * g + 2) * 16384 + wave * 4096 + lane * 16;
            char* dn = (char*)&ktile[(g + 1) & 1][0] + wave * 4096;
#pragma unroll
            for (int sub = 0; sub < 2; sub++)
#pragma unroll
                for (int it = 0; it < 4; it++)
                    gld16(sn + sub * 16384 + it * 1024, dn + sub * 16384 + it * 1024);
        }

#pragma unroll
        for (int sub = 0; sub < 2; sub++) {
            const int t = 2 * g + sub;
            const uint16_t* kt = &ktile[g & 1][sub * 8192];
            f32x16 acc0, acc1;    // 2 independent chains (one per rowtile)
#pragma unroll
            for (int i = 0; i < 16; i++) { acc0[i] = 0.0f; acc1[i] = 0.0f; }
#pragma unroll
            for (int a0 = 0; a0 < 16; a0++) {
                bf16x8 b = __builtin_bit_cast(bf16x8,
                    *(const u16x8*)&kt[(size_t)(a0 * 64 + lane) * 8]);
                acc0 = __builtin_amdgcn_mfma_f32_32x32x16_bf16(q0[a0], b, acc0, 0, 0, 0);
                acc1 = __builtin_amdgcn_mfma_f32_32x32x16_bf16(q1[a0], b, acc1, 0, 0, 0);
            }

            if (MODE == 0) {
#pragma unroll
                for (int r = 0; r < 16; r++) {
                    rs0[r] += fexp2(acc0[r]);
                    rs1[r] += fexp2(acc1[r]);
                }
            } else {
                float sv = 0.0f;
#pragma unroll
                for (int r = 0; r < 16; r++) {
                    sv += fexp2(acc0[r]) * rr0[r];
                    sv += fexp2(acc1[r]) * rr1[r];
                }
                sv += __shfl_xor(sv, 32);             // fold row halves per col
                if (lane < 32) atomicAdd(&c_lds[t * 32 + lane], sv);
            }
        }
    }

    if (MODE == 0) {
#pragma unroll
        for (int r = 0; r < 16; r++) {
            float v0 = rs0[r], v1 = rs1[r];
            v0 += __shfl_xor(v0, 1);  v0 += __shfl_xor(v0, 2);
            v0 += __shfl_xor(v0, 4);  v0 += __shfl_xor(v0, 8);
            v0 += __shfl_xor(v0, 16);
            v1 += __shfl_xor(v1, 1);  v1 += __shfl_xor(v1, 2);
            v1 += __shfl_xor(v1, 4);  v1 += __shfl_xor(v1, 8);
            v1 += __shfl_xor(v1, 16);
            if ((lane & 31) == 0) {
                int ro = (r & 3) + 8 * (r >> 2) + 4 * (lane >> 5);
                atomicAdd(&l_arr[row0 + ro], v0);
                atomicAdd(&l_arr[row0 + 32 + ro], v1);
            }
        }
    } else {
        __syncthreads();
        for (int i = tid; i < 512; i += 256)
            atomicAdd(&c_arr[cc * 512 + i], c_lds[i]);
    }
}

// ---------------------------------------------------------------------------
// Kernel 4 (R8 verbatim): x = c @ h. 256 blocks x 32 rows, fully unrolled.
// ---------------------------------------------------------------------------
__global__ __launch_bounds__(256) void finish_kernel(
        const float* __restrict__ h, const float* __restrict__ c_arr,
        float* __restrict__ out) {
    const int d = threadIdx.x;
    const int j0 = blockIdx.x * 32;
    float acc = 0.0f;
#pragma unroll
    for (int jj = 0; jj < 32; jj++)
        acc += c_arr[j0 + jj] * h[(size_t)(j0 + jj) * DIM + d];
    atomicAdd(&out[d], acc);
}

// ---------------------------------------------------------------------------
extern "C" void kernel_launch(void* const* d_in, const int* in_sizes, int n_in,
                              void* d_out, int out_size, void* d_ws, size_t ws_size,
                              hipStream_t stream) {
    const float* h  = (const float*)d_in[0];
    const float* Wq = (const float*)d_in[1];
    const float* Wk = (const float*)d_in[2];

    // ws layout identical to R5..R10 (proven high-water 8,454,144 B)
    uint16_t* qf = (uint16_t*)d_ws;
    uint16_t* kf = qf + (size_t)N_ROWS * DIM;                  // +4 MB
    float* l_arr = (float*)((char*)d_ws + (size_t)8 * 1024 * 1024);
    float* c_arr = l_arr + N_ROWS;
    float* out = (float*)d_out;

    proj_kernel<<<1024, 256, 0, stream>>>(h, Wq, Wk, qf, kf, l_arr, c_arr, out);
    qk_pass<0><<<512, 256, 0, stream>>>(qf, kf, l_arr, c_arr);
    qk_pass<1><<<512, 256, 0, stream>>>(qf, kf, l_arr, c_arr);
    finish_kernel<<<256, 256, 0, stream>>>(h, c_arr, out);
}

// Round 12
// 147.446 us; speedup vs baseline: 1.3615x; 1.0568x over previous
//
#include <hip/hip_runtime.h>
#include <cstdint>
#include <cstddef>

// ---------------------------------------------------------------------------
// x = mean_i( softmax(q_i K^T / 16) ) @ h   with q = h@Wq, k = h@Wk
//   = sum_j c_j h_j,  c_j = (1/N) sum_i exp(e_ij)/l_i,  l_i = sum_j exp(e_ij)
//
// Round 12: qk_pass occupancy fix via geometry. R11 audit: pipes sum ~80% of
// wall at ~1.3 waves/SIMD; per-wave ~268 unified regs > 256 blocked the 2nd
// 256-thread block. New shape: 512-thread blocks, 8 waves x 2 rowtiles,
// grid 256 = 1 block/CU -> 2 waves/SIMD co-resident BY CONSTRUCTION
// (launch_bounds(512,2) caps at 256 regs). k-tile staged once per 512 rows:
// LDS/CU/pass 4.5 -> 2.25 MB (11us < 13.8us MFMA floor), L2 k-traffic halves.
// Fragment/epilogue/staging code identical; proj/finish unchanged (controls).
//
// ws: R5..R11 layout: [0,4MB) q bf16 frag-major | [4MB,8MB) k frag-major |
//     l fp32[8192] | c fp32[8192]
// Frag-major (32x32 MFMA A/B layout) per 32-row tile = 16 KB:
//   elem (i,d): tile i>>5, slot (d>>4)*64 + (i&31) + 32*((d>>3)&1), byte d&7;
//   dword index within tile = a0*64 + lane (lane-linear 16B).
// ---------------------------------------------------------------------------

#define N_ROWS 8192
#define DIM    256

typedef __bf16 bf16x8 __attribute__((ext_vector_type(8)));
typedef unsigned short u16x8 __attribute__((ext_vector_type(8)));
typedef float f32x16 __attribute__((ext_vector_type(16)));

__device__ __forceinline__ uint16_t f2bf(float f) {
    uint32_t u = __float_as_uint(f);
    uint32_t r = (u + 0x7fffu + ((u >> 16) & 1u)) >> 16;   // RTN-even
    return (uint16_t)r;
}

__device__ __forceinline__ float fexp2(float x) {
#if __has_builtin(__builtin_amdgcn_exp2f)
    return __builtin_amdgcn_exp2f(x);                      // v_exp_f32 = 2^x
#else
    return __expf(x * 0.69314718056f);
#endif
}

// async global->LDS, 16B/lane; lds dst is wave-uniform base + lane*16
__device__ __forceinline__ void gld16(const void* gsrc, void* ldst) {
    __builtin_amdgcn_global_load_lds(
        (const __attribute__((address_space(1))) unsigned int*)gsrc,
        (__attribute__((address_space(3))) unsigned int*)ldst, 16, 0, 0);
}

// ---------------------------------------------------------------------------
// Kernel 1 (R11 verbatim): proj. Grid 1024: bid = rt*4 + ph. h staged
// coalesced to LDS (stride-260), W per-lane scalar loads, proven repack.
// Zero-inits l_arr / c_arr / out.
// ---------------------------------------------------------------------------
__global__ __launch_bounds__(256) void proj_kernel(
        const float* __restrict__ h, const float* __restrict__ Wq,
        const float* __restrict__ Wk, uint16_t* __restrict__ qf,
        uint16_t* __restrict__ kf, float* __restrict__ l_arr,
        float* __restrict__ c_arr, float* __restrict__ out) {
    __shared__ alignas(16) float hbf[32 * 260];       // 33.3 KB h stage
    __shared__ alignas(16) uint16_t rep[4][1024];     // 8 KB wave-private repack
    const int tid = threadIdx.x, lane = tid & 63, wave = tid >> 6;
    const int bid = blockIdx.x;
    const int rt = bid >> 2, ph = bid & 3;
    const int which = ph >> 1, p = ph & 1;

    if (bid < 32)       l_arr[bid * 256 + tid] = 0.0f;
    else if (bid < 64)  c_arr[(bid - 32) * 256 + tid] = 0.0f;
    else if (bid == 64) out[tid] = 0.0f;

    const float* __restrict__ W = which ? Wk : Wq;
    uint16_t* __restrict__ dst = which ? kf : qf;
    const float scale = which ? 1.0f : (0.0625f * 1.44269504089f);

    for (int i = tid; i < 2048; i += 256) {
        int r = i >> 6, c = (i & 63) * 4;
        *(float4*)&hbf[r * 260 + c] = *(const float4*)&h[(size_t)(rt * 32 + r) * DIM + c];
    }
    __syncthreads();

    bf16x8 afrag[16];
    {
        const int r = lane & 31;
#pragma unroll
        for (int a0 = 0; a0 < 16; a0++) {
            const int c0 = a0 * 16 + (lane >> 5) * 8;
            float4 f0 = *(const float4*)&hbf[r * 260 + c0];
            float4 f1 = *(const float4*)&hbf[r * 260 + c0 + 4];
            u16x8 f;
            f[0] = f2bf(f0.x); f[1] = f2bf(f0.y); f[2] = f2bf(f0.z); f[3] = f2bf(f0.w);
            f[4] = f2bf(f1.x); f[5] = f2bf(f1.y); f[6] = f2bf(f1.z); f[7] = f2bf(f1.w);
            afrag[a0] = __builtin_bit_cast(bf16x8, f);
        }
    }

    const int ctl = wave;
    const int cl = ctl * 32 + (lane & 31);
    f32x16 acc;
#pragma unroll
    for (int i = 0; i < 16; i++) acc[i] = 0.0f;
#pragma unroll
    for (int a0 = 0; a0 < 16; a0++) {
        const int kb = a0 * 16 + (lane >> 5) * 8;
        u16x8 f;
#pragma unroll
        for (int j = 0; j < 8; j++)
            f[j] = f2bf(W[(size_t)(kb + j) * DIM + p * 128 + cl]);
        acc = __builtin_amdgcn_mfma_f32_32x32x16_bf16(
            afrag[a0], __builtin_bit_cast(bf16x8, f), acc, 0, 0, 0);
    }

    {
        const int dcl = lane & 31;
        const int a0o = dcl >> 4, hi = (dcl >> 3) & 1, jj = dcl & 7;
        const int ilb = 4 * (lane >> 5);
#pragma unroll
        for (int reg = 0; reg < 16; reg++) {
            int il = ilb + (reg & 3) + 8 * (reg >> 2);
            rep[wave][(size_t)((a0o * 64) + il + 32 * hi) * 8 + jj] =
                f2bf(acc[reg] * scale);
        }
        const uint4* rv = (const uint4*)&rep[wave][0];  // wave-local RAW
        uint4* gp = (uint4*)(dst + (size_t)rt * 8192 +
                             (size_t)(p * 4 + ctl) * 1024);
        gp[lane * 2]     = rv[lane * 2];
        gp[lane * 2 + 1] = rv[lane * 2 + 1];
    }
}

// ---------------------------------------------------------------------------
// Kernels 2/3: two QK^T passes, 512-thread blocks. Grid 256 = 16 rowblocks
// (512 rows) x 16 colchunks(512 cols), 1 block/CU, 2 waves/SIMD guaranteed.
// Per barrier group: 32 KB (2 k-tiles) staged async into 2x32KB double
// buffer (each of 8 waves copies 4KB); 8 barriers/pass. Wave: 2 rowtiles
// resident, 2 acc chains. MODE 0: l_i row sums. MODE 1: c_j col sums.
// ---------------------------------------------------------------------------
template <int MODE>
__global__ __launch_bounds__(512, 2) void qk_pass(
        const uint16_t* __restrict__ qf, const uint16_t* __restrict__ kf,
        float* __restrict__ l_arr, float* __restrict__ c_arr) {
    __shared__ alignas(16) uint16_t ktile[2][16384];  // 2 x 32 KB (2 tiles each)
    __shared__ float c_lds[512];
    const int tid = threadIdx.x, lane = tid & 63, wave = tid >> 6;  // wave 0..7
    const int bid = blockIdx.x;
    const int cc = bid & 15, rb = bid >> 4;           // rb 0..15
    const int t0 = rb * 16 + wave * 2;                // wave's rowtiles t0, t0+1
    const int row0 = t0 * 32;

    // resident q: 2 rowtiles x 16 K-chunks = 128 regs
    const uint4* qp = (const uint4*)qf;
    bf16x8 q0[16], q1[16];
#pragma unroll
    for (int a0 = 0; a0 < 16; a0++) {
        q0[a0] = __builtin_bit_cast(bf16x8, qp[(size_t)t0 * 1024 + a0 * 64 + lane]);
        q1[a0] = __builtin_bit_cast(bf16x8, qp[(size_t)(t0 + 1) * 1024 + a0 * 64 + lane]);
    }

    float rs0[16], rs1[16];   // MODE 0 partials
    float rr0[16], rr1[16];   // MODE 1: 1/(N*l_i)
    if (MODE == 0) {
#pragma unroll
        for (int r = 0; r < 16; r++) { rs0[r] = 0.0f; rs1[r] = 0.0f; }
    } else {
#pragma unroll
        for (int r = 0; r < 16; r++) {
            int ro = (r & 3) + 8 * (r >> 2) + 4 * (lane >> 5);
            rr0[r] = 1.0f / (8192.0f * l_arr[row0 + ro]);
            rr1[r] = 1.0f / (8192.0f * l_arr[row0 + 32 + ro]);
        }
        if (tid < 512) c_lds[tid] = 0.0f;
    }

    const char* ksrc = (const char*)kf + (size_t)cc * 16 * 16384;  // 16 tiles

    {   // prologue: stage tiles 0,1 (32 KB) -> buffer 0; each wave 4 KB
        const char* s0 = ksrc + wave * 4096 + lane * 16;
        char* d0 = (char*)&ktile[0][0] + wave * 4096;
#pragma unroll
        for (int it = 0; it < 4; it++) gld16(s0 + it * 1024, d0 + it * 1024);
    }

    for (int g = 0; g < 8; g++) {
        __syncthreads();          // vmcnt drained: group g staged; other
                                  // buffer's readers all done
        if (g < 7) {              // prefetch group g+1 (tiles 2g+2, 2g+3)
            const char* sn = ksrc + (size_t)(2 * g + 2) * 16384 + wave * 4096 + lane * 16;
            char* dn = (char*)&ktile[(g + 1) & 1][0] + wave * 4096;
#pragma unroll
            for (int it = 0; it < 4; it++) gld16(sn + it * 1024, dn + it * 1024);
        }

#pragma unroll
        for (int sub = 0; sub < 2; sub++) {
            const int t = 2 * g + sub;
            const uint16_t* kt = &ktile[g & 1][sub * 8192];
            f32x16 acc0, acc1;    // 2 independent chains (one per rowtile)
#pragma unroll
            for (int i = 0; i < 16; i++) { acc0[i] = 0.0f; acc1[i] = 0.0f; }
#pragma unroll
            for (int a0 = 0; a0 < 16; a0++) {
                bf16x8 b = __builtin_bit_cast(bf16x8,
                    *(const u16x8*)&kt[(size_t)(a0 * 64 + lane) * 8]);
                acc0 = __builtin_amdgcn_mfma_f32_32x32x16_bf16(q0[a0], b, acc0, 0, 0, 0);
                acc1 = __builtin_amdgcn_mfma_f32_32x32x16_bf16(q1[a0], b, acc1, 0, 0, 0);
            }

            if (MODE == 0) {
#pragma unroll
                for (int r = 0; r < 16; r++) {
                    rs0[r] += fexp2(acc0[r]);
                    rs1[r] += fexp2(acc1[r]);
                }
            } else {
                float sv = 0.0f;
#pragma unroll
                for (int r = 0; r < 16; r++) {
                    sv += fexp2(acc0[r]) * rr0[r];
                    sv += fexp2(acc1[r]) * rr1[r];
                }
                sv += __shfl_xor(sv, 32);             // fold row halves per col
                if (lane < 32) atomicAdd(&c_lds[t * 32 + lane], sv);
            }
        }
    }

    if (MODE == 0) {
#pragma unroll
        for (int r = 0; r < 16; r++) {
            float v0 = rs0[r], v1 = rs1[r];
            v0 += __shfl_xor(v0, 1);  v0 += __shfl_xor(v0, 2);
            v0 += __shfl_xor(v0, 4);  v0 += __shfl_xor(v0, 8);
            v0 += __shfl_xor(v0, 16);
            v1 += __shfl_xor(v1, 1);  v1 += __shfl_xor(v1, 2);
            v1 += __shfl_xor(v1, 4);  v1 += __shfl_xor(v1, 8);
            v1 += __shfl_xor(v1, 16);
            if ((lane & 31) == 0) {
                int ro = (r & 3) + 8 * (r >> 2) + 4 * (lane >> 5);
                atomicAdd(&l_arr[row0 + ro], v0);
                atomicAdd(&l_arr[row0 + 32 + ro], v1);
            }
        }
    } else {
        __syncthreads();
        if (tid < 512) atomicAdd(&c_arr[cc * 512 + tid], c_lds[tid]);
    }
}

// ---------------------------------------------------------------------------
// Kernel 4 (R8 verbatim): x = c @ h. 256 blocks x 32 rows, fully unrolled.
// ---------------------------------------------------------------------------
__global__ __launch_bounds__(256) void finish_kernel(
        const float* __restrict__ h, const float* __restrict__ c_arr,
        float* __restrict__ out) {
    const int d = threadIdx.x;
    const int j0 = blockIdx.x * 32;
    float acc = 0.0f;
#pragma unroll
    for (int jj = 0; jj < 32; jj++)
        acc += c_arr[j0 + jj] * h[(size_t)(j0 + jj) * DIM + d];
    atomicAdd(&out[d], acc);
}

// ---------------------------------------------------------------------------
extern "C" void kernel_launch(void* const* d_in, const int* in_sizes, int n_in,
                              void* d_out, int out_size, void* d_ws, size_t ws_size,
                              hipStream_t stream) {
    const float* h  = (const float*)d_in[0];
    const float* Wq = (const float*)d_in[1];
    const float* Wk = (const float*)d_in[2];

    uint16_t* qf = (uint16_t*)d_ws;
    uint16_t* kf = qf + (size_t)N_ROWS * DIM;                  // +4 MB
    float* l_arr = (float*)((char*)d_ws + (size_t)8 * 1024 * 1024);
    float* c_arr = l_arr + N_ROWS;
    float* out = (float*)d_out;

    proj_kernel<<<1024, 256, 0, stream>>>(h, Wq, Wk, qf, kf, l_arr, c_arr, out);
    qk_pass<0><<<256, 512, 0, stream>>>(qf, kf, l_arr, c_arr);
    qk_pass<1><<<256, 512, 0, stream>>>(qf, kf, l_arr, c_arr);
    finish_kernel<<<256, 256, 0, stream>>>(h, c_arr, out);
}